// Round 13
// baseline (173.601 us; speedup 1.0000x reference)
//
#include <hip/hip_runtime.h>
#include <hip/hip_bf16.h>
#include <stdint.h>

#define NPTS 131072
#define DIM  512
#define KC   512
#define BM   64
#define BK   32
#define NKT  16          // DIM / BK

typedef float f32x16 __attribute__((ext_vector_type(16)));
typedef float f32x4  __attribute__((ext_vector_type(4)));
typedef short bf16x8 __attribute__((ext_vector_type(8)));

__device__ __forceinline__ float sq4(f32x4 a) {
  return a.x*a.x + a.y*a.y + a.z*a.z + a.w*a.w;
}

// packed RNE fp32->bf16 (v_cvt_pk_bf16_f32)
__device__ __forceinline__ bf16x8 pack8c(f32x4 a, f32x4 b) {
  union { __hip_bfloat162 h; short s[2]; } u0, u1, u2, u3;
  u0.h = __float22bfloat162_rn(make_float2(a.x, a.y));
  u1.h = __float22bfloat162_rn(make_float2(a.z, a.w));
  u2.h = __float22bfloat162_rn(make_float2(b.x, b.y));
  u3.h = __float22bfloat162_rn(make_float2(b.z, b.w));
  bf16x8 r;
  r[0] = u0.s[0]; r[1] = u0.s[1]; r[2] = u1.s[0]; r[3] = u1.s[1];
  r[4] = u2.s[0]; r[5] = u2.s[1]; r[6] = u3.s[0]; r[7] = u3.s[1];
  return r;
}

// scalar RNE (cluster pre-kernel only)
__device__ __forceinline__ short f2bf(float f) {
  union { float f; unsigned u; } v; v.f = f;
  unsigned r = v.u + 0x7FFFu + ((v.u >> 16) & 1u);
  return (short)(r >> 16);
}
__device__ __forceinline__ bf16x8 pack8(f32x4 a, f32x4 b) {
  bf16x8 p;
  p[0] = f2bf(a.x); p[1] = f2bf(a.y); p[2] = f2bf(a.z); p[3] = f2bf(a.w);
  p[4] = f2bf(b.x); p[5] = f2bf(b.y); p[6] = f2bf(b.z); p[7] = f2bf(b.w);
  return p;
}

__device__ __forceinline__ void gload_lds16(const void* g, void* l) {
  __builtin_amdgcn_global_load_lds(
      (const __attribute__((address_space(1))) unsigned int*)g,
      (__attribute__((address_space(3))) unsigned int*)l, 16, 0, 0);
}

// ---------------------------------------------------------------------------
// Cluster pre-kernel (layout verified R5-R11): fp32 [512][512] -> bf16 in
// MFMA-B-fragment order. Short offset = q*8192 + wn*2048 + nt*512 +
// (h*32+r)*8 where q = kt*2+st is the HALF-KT index — each 16 KB half-tile
// contiguous, staged linearly, fragments read at base + lane*16.
// c2[n] = ||c_n||^2 fp32.
// ---------------------------------------------------------------------------
__global__ void dec_pack(const float* __restrict__ C, short* __restrict__ Bp,
                         float* __restrict__ c2) {
  const int n    = blockIdx.x;
  const int lane = threadIdx.x;
  const float* src = C + (size_t)n * DIM + lane * 8;
  f32x4 v0 = *(const f32x4*)src;
  f32x4 v1 = *(const f32x4*)(src + 4);
  float s = sq4(v0) + sq4(v1);
  #pragma unroll
  for (int m = 1; m < 64; m <<= 1) s += __shfl_xor(s, m, 64);
  if (lane == 0) c2[n] = s;
  const int kt = lane >> 2;
  const int st = (lane >> 1) & 1;
  const int hh = lane & 1;
  const int wn = n >> 7, nt = (n >> 5) & 3, r = n & 31;
  const size_t slot =
      (((size_t)(kt * 2 + st) * 4 + wn) * 4 + nt) * 64 + hh * 32 + r;
  *(bf16x8*)(Bp + slot * 8) = pack8(v0, v1);
}

// ---------------------------------------------------------------------------
// Main fused kernel (R13 = R12 with the gload_lds lane*16 contract fixed).
// 256 threads = 4 waves, wn = wave; block tile 64 x 512.
// Wave tile 64 x 128: mt=2 x nt=4, acc = 8 x f32x16; 8 MFMA per phase.
//
// A staging obeys the HW contract (m104/m108: dest = wave-uniform base +
// lane*16, per-lane dest pointers are IGNORED): two 4 KB calls, each thread
// contributes exactly 16 B at linear dest tid*16B (+4096B for rows 32..63).
//   call c: row = c*32 + (tid>>3), dest chunk d = tid&7,
//           source chunk = d ^ (row&7)   [XOR involution, read side inverts]
// Read side (unchanged): A[row][c] at LDS chunk c ^ (row&7) — verified
// conflict-free (each 8-lane group covers all 32 banks once).
//
// 32 phases. Phase p: [s_waitcnt vmcnt(N); s_barrier] ->
//   [stage: even: B-half(p+2) 4x gload + A(kt+1) 2x gload (6 ops);
//           odd:  B-half(p+2) 4x gload (4 ops)] ->
//   [compute(kt, s=p&1): per mt: 2x A-frag ds_read -> cvt_pk; 4x B-frag
//    ds_read (linear); 8 MFMA; x2 fused from fp32 regs].
// N: even -> vmcnt(4), odd -> vmcnt(6) (wait = previous-phase's group).
// Rings: B 3 x 16 KB, A fp32 2 x 8 KB = 64 KB LDS -> 2 blocks/CU.
// Dead-tail stages keep counts uniform; final __syncthreads drains them
// (vmcnt(0) there is harmless: loop is done) before the epilogue overlay.
// ---------------------------------------------------------------------------
__global__ __launch_bounds__(256, 2)
void dec_main(const float* __restrict__ X, const short* __restrict__ Bp,
              const float* __restrict__ c2g, float* __restrict__ out) {
  __shared__ short Bh[3][8192];     // 3 x 16 KB half-kt B tiles
  __shared__ float Ab[2][2048];     // 2 x 8 KB fp32 A tiles (swizzled chunks)

  const int tid  = threadIdx.x;
  const int lane = tid & 63;
  const int wn   = tid >> 6;    // 0..3 : column quarter (one wave each)
  const int l31  = lane & 31;
  const int h    = lane >> 5;
  const int row0 = blockIdx.x * BM;

  // A staging (lane*16 contract): call c covers row c*32+(tid>>3), dest
  // linear tid*16B (+4096B for c=1); source chunk = (tid&7) ^ (row&7).
  const int art = tid >> 3;     // 0..31
  const int act = tid & 7;      // dest chunk
  const float* asrcL = X + (size_t)(row0 + art) * DIM +
                       ((act ^ (art & 7)) << 2);
  const float* asrcH = X + (size_t)(row0 + 32 + art) * DIM +
                       ((act ^ (art & 7)) << 2);
  // B staging: 4 sweeps of 16 B/thread, linear (pre-packed source)
  const short* bsrc = Bp + tid * 8;

  const int asw = l31 & 7;      // read-side XOR (rows l31 and 32+l31 share it)

  f32x16 acc[2][4];
  #pragma unroll
  for (int mt = 0; mt < 2; ++mt)
    #pragma unroll
    for (int nt = 0; nt < 4; ++nt) acc[mt][nt] = (f32x16)0.f;
  float x2s[2] = {0.f, 0.f};

  // ---- prologue: stage q=0 (+A(0)) [6 ops], then q=1 [4 ops] ----
  #pragma unroll
  for (int sw = 0; sw < 4; ++sw)
    gload_lds16(bsrc + sw * 2048, &Bh[0][sw * 2048 + tid * 8]);
  gload_lds16(asrcL, &Ab[0][tid * 4]);
  gload_lds16(asrcH, &Ab[0][1024 + tid * 4]);
  __builtin_amdgcn_sched_barrier(0);
  #pragma unroll
  for (int sw = 0; sw < 4; ++sw)
    gload_lds16(bsrc + 8192 + sw * 2048, &Bh[1][sw * 2048 + tid * 8]);
  __builtin_amdgcn_sched_barrier(0);

  int rb = 0;   // Bh ring position of (kt, s=0)
  for (int kt = 0; kt < NKT; ++kt) {
    const int rb1 = (rb == 2) ? 0 : rb + 1;   // (kt,s=1) buffer
    const int rb2 = (rb == 0) ? 2 : rb - 1;   // stage target for even phase

    // ================= even phase p = 2kt =================
    asm volatile("s_waitcnt vmcnt(4)" ::: "memory");
    __builtin_amdgcn_sched_barrier(0);
    __builtin_amdgcn_s_barrier();
    __builtin_amdgcn_sched_barrier(0);
    {
      const int q  = (2 * kt + 2 < 32) ? 2 * kt + 2 : 31;   // B half index
      const int ka = (kt + 1 < NKT) ? kt + 1 : NKT - 1;     // A tile index
      #pragma unroll
      for (int sw = 0; sw < 4; ++sw)
        gload_lds16(bsrc + (size_t)q * 8192 + sw * 2048,
                    &Bh[rb2][sw * 2048 + tid * 8]);
      gload_lds16(asrcL + ka * BK, &Ab[(kt + 1) & 1][tid * 4]);
      gload_lds16(asrcH + ka * BK, &Ab[(kt + 1) & 1][1024 + tid * 4]);
    }
    __builtin_amdgcn_sched_barrier(0);
    {
      const float* A = &Ab[kt & 1][0];
      bf16x8 af[2];
      #pragma unroll
      for (int mt = 0; mt < 2; ++mt) {
        f32x4 lo = *(const f32x4*)
            &A[mt * 1024 + l31 * 32 + (((h * 2 + 0) ^ asw) << 2)];
        f32x4 hi = *(const f32x4*)
            &A[mt * 1024 + l31 * 32 + (((h * 2 + 1) ^ asw) << 2)];
        x2s[mt] += sq4(lo) + sq4(hi);
        af[mt] = pack8c(lo, hi);
      }
      bf16x8 bfr[4];
      #pragma unroll
      for (int nt = 0; nt < 4; ++nt)
        bfr[nt] = *(const bf16x8*)&Bh[rb][(wn * 4 + nt) * 512 + lane * 8];
      #pragma unroll
      for (int mt = 0; mt < 2; ++mt)
        #pragma unroll
        for (int nt = 0; nt < 4; ++nt)
          acc[mt][nt] = __builtin_amdgcn_mfma_f32_32x32x16_bf16(
              af[mt], bfr[nt], acc[mt][nt], 0, 0, 0);
    }

    // ================= odd phase p = 2kt+1 =================
    asm volatile("s_waitcnt vmcnt(6)" ::: "memory");
    __builtin_amdgcn_sched_barrier(0);
    __builtin_amdgcn_s_barrier();
    __builtin_amdgcn_sched_barrier(0);
    {
      const int q = (2 * kt + 3 < 32) ? 2 * kt + 3 : 31;
      #pragma unroll
      for (int sw = 0; sw < 4; ++sw)
        gload_lds16(bsrc + (size_t)q * 8192 + sw * 2048,
                    &Bh[rb][sw * 2048 + tid * 8]);
    }
    __builtin_amdgcn_sched_barrier(0);
    {
      const float* A = &Ab[kt & 1][0];
      bf16x8 af[2];
      #pragma unroll
      for (int mt = 0; mt < 2; ++mt) {
        f32x4 lo = *(const f32x4*)
            &A[mt * 1024 + l31 * 32 + (((4 + h * 2 + 0) ^ asw) << 2)];
        f32x4 hi = *(const f32x4*)
            &A[mt * 1024 + l31 * 32 + (((4 + h * 2 + 1) ^ asw) << 2)];
        x2s[mt] += sq4(lo) + sq4(hi);
        af[mt] = pack8c(lo, hi);
      }
      bf16x8 bfr[4];
      #pragma unroll
      for (int nt = 0; nt < 4; ++nt)
        bfr[nt] = *(const bf16x8*)&Bh[rb1][(wn * 4 + nt) * 512 + lane * 8];
      #pragma unroll
      for (int mt = 0; mt < 2; ++mt)
        #pragma unroll
        for (int nt = 0; nt < 4; ++nt)
          acc[mt][nt] = __builtin_amdgcn_mfma_f32_32x32x16_bf16(
              af[mt], bfr[nt], acc[mt][nt], 0, 0, 0);
    }

    rb = (rb + 2 >= 3) ? rb - 1 : rb + 2;   // (rb + 2) % 3
  }

  // drain dead tail stages before overlaying epilogue scratch on Ab
  __syncthreads();

  // ---- x2: combine the two k-halves; lane holds x2(rows mt*32+l31) ----
  #pragma unroll
  for (int mt = 0; mt < 2; ++mt) x2s[mt] += __shfl_xor(x2s[mt], 32, 64);

  float c2v[4];
  #pragma unroll
  for (int nt = 0; nt < 4; ++nt) c2v[nt] = c2g[wn * 128 + nt * 32 + l31];

  // ---- q = rcp(1+d2), per-row partial sums over this wave's 128 cols ----
  float srow[2][16];
  #pragma unroll
  for (int mt = 0; mt < 2; ++mt) {
    #pragma unroll
    for (int r = 0; r < 16; ++r) {
      const int mloc = (r & 3) + 8 * (r >> 2) + 4 * h;   // 0..31
      const float x2m = __shfl(x2s[mt], mloc, 64);
      float s = 0.f;
      #pragma unroll
      for (int nt = 0; nt < 4; ++nt) {
        float d2 = fmaxf(x2m + c2v[nt] - 2.f * acc[mt][nt][r], 0.f);
        float q = __builtin_amdgcn_rcpf(1.f + d2);
        acc[mt][nt][r] = q;
        s += q;
      }
      #pragma unroll
      for (int msk = 1; msk < 32; msk <<= 1) s += __shfl_xor(s, msk, 64);
      srow[mt][r] = s;
    }
  }

  // epilogue scratch overlaid on Ab (dead after the drain barrier)
  float* part   = &Ab[0][0];        // [4][BM]
  float* rowinv = &Ab[0][4 * BM];

  if (l31 == 0) {
    #pragma unroll
    for (int mt = 0; mt < 2; ++mt)
      #pragma unroll
      for (int r = 0; r < 16; ++r)
        part[wn * BM + mt * 32 + (r & 3) + 8 * (r >> 2) + 4 * h] = srow[mt][r];
  }
  __syncthreads();
  if (tid < BM)
    rowinv[tid] = __builtin_amdgcn_rcpf(part[tid] + part[BM + tid] +
                                        part[2 * BM + tid] + part[3 * BM + tid]);
  __syncthreads();

  // ---- normalize + coalesced stores ----
  #pragma unroll
  for (int mt = 0; mt < 2; ++mt) {
    #pragma unroll
    for (int r = 0; r < 16; ++r) {
      const int row = mt * 32 + (r & 3) + 8 * (r >> 2) + 4 * h;
      const float iv = rowinv[row];
      float* o = out + (size_t)(row0 + row) * KC + wn * 128 + l31;
      #pragma unroll
      for (int nt = 0; nt < 4; ++nt)
        o[nt * 32] = acc[mt][nt][r] * iv;
    }
  }
}

extern "C" void kernel_launch(void* const* d_in, const int* in_sizes, int n_in,
                              void* d_out, int out_size, void* d_ws, size_t ws_size,
                              hipStream_t stream) {
  const float* X = (const float*)d_in[0];   // inputs  [131072, 512] fp32
  const float* C = (const float*)d_in[1];   // clusters [512, 512] fp32
  float* out = (float*)d_out;               // [131072, 512] fp32

  short* Bp = (short*)d_ws;                                   // 512 KB packed bf16 clusters
  float* c2 = (float*)((char*)d_ws + (size_t)KC * DIM * 2);   // 2 KB cluster norms

  dec_pack<<<KC, 64, 0, stream>>>(C, Bp, c2);
  dec_main<<<NPTS / BM, 256, 0, stream>>>(X, Bp, c2, out);
}